// Round 1
// 359.278 us; speedup vs baseline: 1.0569x; 1.0569x over previous
//
#include <hip/hip_runtime.h>
#include <hip/hip_bf16.h>
#include <stdint.h>

// B=4, L=1024, C=768, H=12, D=64.  All inputs/outputs fp32.
// Pipeline (all-MFMA bf16, fp32 accumulate):
//   c1: cast x, w_qkv, w_proj -> bf16 ws (single fused launch)
//   k1: qkv GEMM  [4096x768]@[2304x768]^T -> scatter q(pre*0.125),k [bh][l][d], v^T [bh][d][l]  (bf16)
//   k2: attention per (bh, 16 rows): swapped QK^T (lane owns a full S row slice in regs)
//       -> register softmax -> out1 fp32 from regs + normalized bf16 S in LDS -> PV MFMA -> attn_o bf16
//   k3: proj GEMM  [4096x768]@[768x768]^T + bias -> out0 fp32

typedef __attribute__((ext_vector_type(8))) short short8;
typedef __attribute__((ext_vector_type(4))) float floatx4;

#define MFMA16(A_, B_, C_) __builtin_amdgcn_mfma_f32_16x16x32_bf16((A_), (B_), (C_), 0, 0, 0)

__device__ __forceinline__ unsigned short f2bf(float f) {
  unsigned u = __builtin_bit_cast(unsigned, f);
  u += 0x7FFFu + ((u >> 16) & 1u);   // round-to-nearest-even
  return (unsigned short)(u >> 16);
}
__device__ __forceinline__ float bf2f(unsigned short u) {
  return __builtin_bit_cast(float, (unsigned)u << 16);
}

// ---------------- fused cast fp32 -> bf16 (x, w_qkv, w_proj; contiguous dst) ----------------
__global__ __launch_bounds__(256) void cast3_kernel(const float* __restrict__ x,
                                                    const float* __restrict__ wq,
                                                    const float* __restrict__ wp,
                                                    unsigned short* __restrict__ dst) {
  const int NX = 3145728, NWQ = 1769472;  // region boundaries are block-aligned
  int i = (blockIdx.x * 256 + threadIdx.x) * 4;
  const float* src;
  int off;
  if (i < NX) { src = x; off = i; }
  else if (i < NX + NWQ) { src = wq; off = i - NX; }
  else { src = wp; off = i - NX - NWQ; }
  float4 v = *(const float4*)(src + off);
  ushort4 o;
  o.x = f2bf(v.x); o.y = f2bf(v.y); o.z = f2bf(v.z); o.w = f2bf(v.w);
  *(ushort4*)(dst + i) = o;
}

// ---------------- bf16 MFMA GEMM: C[M][N] = A[M][K] @ Bm[N][K]^T ----------------
// tile 128x128, BK=32, 256 threads = 4 waves (wave (wm,wn) owns a 64x64 quadrant).
// EPI 0: qkv scatter epilogue.  EPI 1: fp32 C + bias epilogue.
template <int EPI>
__global__ __launch_bounds__(256) void gemm_bt(
    const unsigned short* __restrict__ A, const unsigned short* __restrict__ Bm,
    const float* __restrict__ bias,
    unsigned short* __restrict__ q_ws, unsigned short* __restrict__ k_ws,
    unsigned short* __restrict__ vt_ws, float* __restrict__ Cout,
    int M, int N, int K) {
  __shared__ __align__(16) unsigned short Al[128 * 32];
  __shared__ __align__(16) unsigned short Bl[128 * 32];
  const int tid = threadIdx.x;
  const int lane = tid & 63, wave = tid >> 6;
  const int q = lane >> 4, lm = lane & 15;
  const int wm = wave >> 1, wn = wave & 1;
  const int m0 = blockIdx.y * 128, n0 = blockIdx.x * 128;

  floatx4 acc[4][4];
#pragma unroll
  for (int i = 0; i < 4; ++i)
#pragma unroll
    for (int j = 0; j < 4; ++j) acc[i][j] = (floatx4){0.f, 0.f, 0.f, 0.f};

  for (int k0 = 0; k0 < K; k0 += 32) {
#pragma unroll
    for (int it = 0; it < 2; ++it) {
      int idx = tid + it * 256;  // 0..511 -> row = idx/4, 16B chunk = idx%4
      int row = idx >> 2, ch = idx & 3;
      const unsigned short* ga = A + (size_t)(m0 + row) * K + k0 + ch * 8;
      const unsigned short* gb = Bm + (size_t)(n0 + row) * K + k0 + ch * 8;
      __builtin_amdgcn_global_load_lds(
          (const __attribute__((address_space(1))) unsigned int*)ga,
          (__attribute__((address_space(3))) unsigned int*)(Al + idx * 8), 16, 0, 0);
      __builtin_amdgcn_global_load_lds(
          (const __attribute__((address_space(1))) unsigned int*)gb,
          (__attribute__((address_space(3))) unsigned int*)(Bl + idx * 8), 16, 0, 0);
    }
    __syncthreads();
    short8 af[4], bfr[4];
#pragma unroll
    for (int t = 0; t < 4; ++t) {
      af[t] = *(const short8*)(Al + (wm * 64 + t * 16 + lm) * 32 + q * 8);
      bfr[t] = *(const short8*)(Bl + (wn * 64 + t * 16 + lm) * 32 + q * 8);
    }
#pragma unroll
    for (int i = 0; i < 4; ++i)
#pragma unroll
      for (int j = 0; j < 4; ++j) acc[i][j] = MFMA16(af[i], bfr[j], acc[i][j]);
    __syncthreads();
  }

  if (EPI == 0) {
    // scatter to q_ws/k_ws [bh][l][64] (bf16 scalar) and vt_ws [bh][d][1024] (packed ushort4)
#pragma unroll
    for (int i = 0; i < 4; ++i) {
      int mb = m0 + wm * 64 + i * 16 + q * 4;  // multiple of 4 -> rg stays in one (b,l) row group
#pragma unroll
      for (int j = 0; j < 4; ++j) {
        int n = n0 + wn * 64 + j * 16 + lm;
        int which = n / 768;
        int r = n - which * 768;
        int h = r >> 6, d = r & 63;
        if (which == 2) {
          int b = mb >> 10, l = mb & 1023;  // mb..mb+3: same b, consecutive l
          ushort4 pk;
          pk.x = f2bf(acc[i][j][0]);
          pk.y = f2bf(acc[i][j][1]);
          pk.z = f2bf(acc[i][j][2]);
          pk.w = f2bf(acc[i][j][3]);
          *(ushort4*)(vt_ws + (size_t)((b * 12 + h) * 64 + d) * 1024 + l) = pk;
        } else {
          unsigned short* dst = (which == 0) ? q_ws : k_ws;
          float sc = (which == 0) ? 0.125f : 1.0f;  // fold attention scale into q (exact in bf16)
#pragma unroll
          for (int rg = 0; rg < 4; ++rg) {
            int m = mb + rg;
            int b = m >> 10, l = m & 1023;
            dst[(size_t)((b * 12 + h) * 1024 + l) * 64 + d] = f2bf(acc[i][j][rg] * sc);
          }
        }
      }
    }
  } else {
#pragma unroll
    for (int i = 0; i < 4; ++i) {
      int mb = m0 + wm * 64 + i * 16 + q * 4;
#pragma unroll
      for (int j = 0; j < 4; ++j) {
        int n = n0 + wn * 64 + j * 16 + lm;
        float bv = bias[n];
#pragma unroll
        for (int rg = 0; rg < 4; ++rg) {
          int m = mb + rg;
          Cout[(size_t)m * N + n] = acc[i][j][rg] + bv;
        }
      }
    }
  }
}

// ---------------- attention ----------------
// grid (64, 48): 16 query rows per block, 256 threads = 4 waves; wave owns 256 key cols.
// Swapped QK^T: C = MFMA(K_frag, Q_frag) -> C[m=key][n=q-row]; lane (q,lm) holds
// q-row lm, keys (wave*16+ct)*16 + q*4 + rg  => full row slice lives in acc[16][4] regs.
__global__ __launch_bounds__(256) void attn_mfma(
    const unsigned short* __restrict__ q_ws, const unsigned short* __restrict__ k_ws,
    const unsigned short* __restrict__ vt_ws, unsigned short* __restrict__ attn_o,
    float* __restrict__ out1) {
  constexpr int L = 1024, SW = 1032;  // stride: 16B-aligned rows (2064B = 516 banks, 4 mod 32)
  __shared__ __align__(16) unsigned short S[16 * SW];
  __shared__ float stats[2][4][16];  // [max|sum][wave][row]
  const int bh = blockIdx.y, b = bh / 12, h = bh % 12;
  const int l0 = blockIdx.x * 16;
  const int tid = threadIdx.x, lane = tid & 63, wave = tid >> 6;
  const int q = lane >> 4, lm = lane & 15;

  const size_t qk_base = (size_t)bh * L * 64;

  // Q as B-fragment: B[n=q-row=lm][k=q*8+j]; q pre-scaled by 0.125
  const unsigned short* qr = q_ws + qk_base + (size_t)(l0 + lm) * 64;
  short8 bq0 = *(const short8*)(qr + q * 8);
  short8 bq1 = *(const short8*)(qr + 32 + q * 8);

  // ---- swapped QK^T into registers ----
  floatx4 acc[16];
#pragma unroll
  for (int ct = 0; ct < 16; ++ct) {
    const unsigned short* kr = k_ws + qk_base + (size_t)((wave * 16 + ct) * 16 + lm) * 64;
    short8 a0 = *(const short8*)(kr + q * 8);
    short8 a1 = *(const short8*)(kr + 32 + q * 8);
    floatx4 c = (floatx4){0.f, 0.f, 0.f, 0.f};
    c = MFMA16(a0, bq0, c);
    c = MFMA16(a1, bq1, c);
    acc[ct] = c;
  }

  // ---- register softmax: row r = lm, spread over 4 lanes (q) x 16 cts ----
  float mloc = -1e30f;
#pragma unroll
  for (int ct = 0; ct < 16; ++ct)
#pragma unroll
    for (int rg = 0; rg < 4; ++rg) mloc = fmaxf(mloc, acc[ct][rg]);
  mloc = fmaxf(mloc, __shfl_xor(mloc, 16));
  mloc = fmaxf(mloc, __shfl_xor(mloc, 32));
  if (lane < 16) stats[0][wave][lane] = mloc;
  __syncthreads();
  float m = fmaxf(fmaxf(stats[0][0][lm], stats[0][1][lm]),
                  fmaxf(stats[0][2][lm], stats[0][3][lm]));

  float ssum = 0.f;
#pragma unroll
  for (int ct = 0; ct < 16; ++ct) {
#pragma unroll
    for (int rg = 0; rg < 4; ++rg) {
      float e = exp2f((acc[ct][rg] - m) * 1.44269504f);
      acc[ct][rg] = e;
      ssum += e;
    }
  }
  ssum += __shfl_xor(ssum, 16);
  ssum += __shfl_xor(ssum, 32);
  if (lane < 16) stats[1][wave][lane] = ssum;
  __syncthreads();
  float sinv = 1.0f / (stats[1][0][lm] + stats[1][1][lm] + stats[1][2][lm] + stats[1][3][lm]);

  // ---- write normalized S (bf16, for PV) + out1 (fp32) straight from registers ----
  float* orow = out1 + (size_t)bh * L * L + (size_t)(l0 + lm) * L + wave * 256 + q * 4;
  unsigned short* srow = S + lm * SW + wave * 256 + q * 4;
#pragma unroll
  for (int ct = 0; ct < 16; ++ct) {
    float p0 = acc[ct][0] * sinv, p1 = acc[ct][1] * sinv;
    float p2 = acc[ct][2] * sinv, p3 = acc[ct][3] * sinv;
    ushort4 pk;
    pk.x = f2bf(p0); pk.y = f2bf(p1); pk.z = f2bf(p2); pk.w = f2bf(p3);
    *(ushort4*)(srow + ct * 16) = pk;
    float4 pv;
    pv.x = p0; pv.y = p1; pv.z = p2; pv.w = p3;
    *(float4*)(orow + ct * 16) = pv;
  }
  __syncthreads();

  // ---- PV: wave owns d-tile [wave*16, wave*16+16); S pre-normalized ----
  {
    floatx4 pacc = (floatx4){0.f, 0.f, 0.f, 0.f};
    const unsigned short* vr = vt_ws + (size_t)(bh * 64 + wave * 16 + lm) * 1024;
#pragma unroll 4
    for (int ks = 0; ks < 32; ++ks) {
      short8 af = *(const short8*)(S + lm * SW + ks * 32 + q * 8);  // one ds_read_b128
      short8 bv = *(const short8*)(vr + ks * 32 + q * 8);
      pacc = MFMA16(af, bv, pacc);
    }
#pragma unroll
    for (int rg = 0; rg < 4; ++rg) {
      int row = q * 4 + rg;
      attn_o[(size_t)(b * 1024 + l0 + row) * 768 + h * 64 + wave * 16 + lm] = f2bf(pacc[rg]);
    }
  }
}

extern "C" void kernel_launch(void* const* d_in, const int* in_sizes, int n_in,
                              void* d_out, int out_size, void* d_ws, size_t ws_size,
                              hipStream_t stream) {
  const float* x      = (const float*)d_in[0];  // [4,1024,768]
  const float* w_qkv  = (const float*)d_in[1];  // [2304,768]
  const float* w_proj = (const float*)d_in[2];  // [768,768]
  const float* b_proj = (const float*)d_in[3];  // [768]

  float* out0 = (float*)d_out;                   // [4096,768]
  float* out1 = out0 + (size_t)4096 * 768;       // [48,1024,1024]

  const size_t NX = (size_t)4096 * 768;   // 3,145,728
  const size_t NWQ = (size_t)2304 * 768;  // 1,769,472
  const size_t NWP = (size_t)768 * 768;   //   589,824
  const size_t NQ = (size_t)48 * 1024 * 64;

  unsigned short* x_bf   = (unsigned short*)d_ws;
  unsigned short* wq_bf  = x_bf + NX;
  unsigned short* wp_bf  = wq_bf + NWQ;
  unsigned short* q_ws   = wp_bf + NWP;
  unsigned short* k_ws   = q_ws + NQ;
  unsigned short* vt_ws  = k_ws + NQ;
  unsigned short* attn_o = vt_ws + NQ;   // [4096][768] bf16

  // 1) fused casts (dst regions contiguous from x_bf)
  cast3_kernel<<<dim3((NX + NWQ + NWP) / 1024), dim3(256), 0, stream>>>(x, w_qkv, w_proj, x_bf);

  // 2) qkv GEMM + scatter
  gemm_bt<0><<<dim3(2304 / 128, 4096 / 128), dim3(256), 0, stream>>>(
      x_bf, wq_bf, nullptr, q_ws, k_ws, vt_ws, nullptr, 4096, 2304, 768);

  // 3) attention
  attn_mfma<<<dim3(64, 48), dim3(256), 0, stream>>>(q_ws, k_ws, vt_ws, attn_o, out1);

  // 4) proj GEMM + bias
  gemm_bt<1><<<dim3(768 / 128, 4096 / 128), dim3(256), 0, stream>>>(
      attn_o, wp_bf, b_proj, nullptr, nullptr, nullptr, out0, 4096, 768, 768);
}

// Round 2
// 357.176 us; speedup vs baseline: 1.0631x; 1.0059x over previous
//
#include <hip/hip_runtime.h>
#include <hip/hip_bf16.h>
#include <stdint.h>

// B=4, L=1024, C=768, H=12, D=64.  All inputs/outputs fp32.
// Pipeline (all-MFMA bf16, fp32 accumulate):
//   c1: cast x, w_qkv, w_proj -> bf16 ws (single fused launch)
//   k1: qkv GEMM  [4096x768]@[2304x768]^T (128x128 tile, double-buffered prefetch)
//       -> scatter q(pre*0.125),k [bh][l][d], v^T [bh][d][l]  (bf16)
//   k2: attention per (bh, 16 rows): swapped QK^T -> register softmax -> out1 fp32
//       from regs + normalized bf16 S in LDS -> PV MFMA -> attn_o bf16
//   k3: proj GEMM  [4096x768]@[768x768]^T + bias (128x64 tile -> 384 blocks) -> out0 fp32

typedef __attribute__((ext_vector_type(8))) short short8;
typedef __attribute__((ext_vector_type(4))) float floatx4;

#define MFMA16(A_, B_, C_) __builtin_amdgcn_mfma_f32_16x16x32_bf16((A_), (B_), (C_), 0, 0, 0)

__device__ __forceinline__ unsigned short f2bf(float f) {
  unsigned u = __builtin_bit_cast(unsigned, f);
  u += 0x7FFFu + ((u >> 16) & 1u);   // round-to-nearest-even
  return (unsigned short)(u >> 16);
}
__device__ __forceinline__ float bf2f(unsigned short u) {
  return __builtin_bit_cast(float, (unsigned)u << 16);
}

// ---------------- fused cast fp32 -> bf16 (x, w_qkv, w_proj; contiguous dst) ----------------
__global__ __launch_bounds__(256) void cast3_kernel(const float* __restrict__ x,
                                                    const float* __restrict__ wq,
                                                    const float* __restrict__ wp,
                                                    unsigned short* __restrict__ dst) {
  const int NX = 3145728, NWQ = 1769472;  // region boundaries are block-aligned
  int i = (blockIdx.x * 256 + threadIdx.x) * 4;
  const float* src;
  int off;
  if (i < NX) { src = x; off = i; }
  else if (i < NX + NWQ) { src = wq; off = i - NX; }
  else { src = wp; off = i - NX - NWQ; }
  float4 v = *(const float4*)(src + off);
  ushort4 o;
  o.x = f2bf(v.x); o.y = f2bf(v.y); o.z = f2bf(v.z); o.w = f2bf(v.w);
  *(ushort4*)(dst + i) = o;
}

// ---------------- bf16 MFMA GEMM: C[M][N] = A[M][K] @ Bm[N][K]^T ----------------
// tile 128xBN, BK=32, 256 threads = 4 waves.  Wave (wm,wn) owns a 64x(BN/2) quadrant.
// Double-buffered LDS; next K-tile's global_load_lds issued BEFORE compute of current
// (T3-minimum 2-phase): one barrier per K-step, vmcnt drain overlapped with MFMA.
// EPI 0: qkv scatter epilogue (BN=128 only).  EPI 1: fp32 C + bias epilogue.
template <int EPI, int BN>
__global__ __launch_bounds__(256) void gemm_bt(
    const unsigned short* __restrict__ A, const unsigned short* __restrict__ Bm,
    const float* __restrict__ bias,
    unsigned short* __restrict__ q_ws, unsigned short* __restrict__ k_ws,
    unsigned short* __restrict__ vt_ws, float* __restrict__ Cout,
    int M, int N, int K) {
  constexpr int NJ = BN / 32;  // N-frags per wave (4 or 2)
  constexpr int QN = BN / 2;   // wave quadrant N-size (64 or 32)
  __shared__ __align__(16) unsigned short Al[2][128 * 32];
  __shared__ __align__(16) unsigned short Bl[2][BN * 32];
  const int tid = threadIdx.x;
  const int lane = tid & 63, wave = tid >> 6;
  const int q = lane >> 4, lm = lane & 15;
  const int wm = wave >> 1, wn = wave & 1;
  const int m0 = blockIdx.y * 128, n0 = blockIdx.x * BN;

  floatx4 acc[4][NJ];
#pragma unroll
  for (int i = 0; i < 4; ++i)
#pragma unroll
    for (int j = 0; j < NJ; ++j) acc[i][j] = (floatx4){0.f, 0.f, 0.f, 0.f};

  auto stage = [&](int k0, int buf) {
    // A: 128 rows x 32 cols = 512 16B-chunks
#pragma unroll
    for (int it = 0; it < 2; ++it) {
      int idx = tid + it * 256;
      int row = idx >> 2, ch = idx & 3;
      const unsigned short* ga = A + (size_t)(m0 + row) * K + k0 + ch * 8;
      __builtin_amdgcn_global_load_lds(
          (const __attribute__((address_space(1))) unsigned int*)ga,
          (__attribute__((address_space(3))) unsigned int*)(&Al[buf][0] + idx * 8), 16, 0, 0);
    }
    // B: BN rows x 32 cols = BN*4 16B-chunks
#pragma unroll
    for (int it = 0; it < BN / 64; ++it) {
      int idx = tid + it * 256;
      int row = idx >> 2, ch = idx & 3;
      const unsigned short* gb = Bm + (size_t)(n0 + row) * K + k0 + ch * 8;
      __builtin_amdgcn_global_load_lds(
          (const __attribute__((address_space(1))) unsigned int*)gb,
          (__attribute__((address_space(3))) unsigned int*)(&Bl[buf][0] + idx * 8), 16, 0, 0);
    }
  };

  stage(0, 0);
  __syncthreads();  // drains vmcnt(0): buf0 ready
  int cur = 0;
  for (int k0 = 0; k0 < K; k0 += 32) {
    if (k0 + 32 < K) stage(k0 + 32, cur ^ 1);  // prefetch next tile, in flight during MFMA
    short8 af[4], bfr[NJ];
#pragma unroll
    for (int t = 0; t < 4; ++t)
      af[t] = *(const short8*)(&Al[cur][0] + (wm * 64 + t * 16 + lm) * 32 + q * 8);
#pragma unroll
    for (int t = 0; t < NJ; ++t)
      bfr[t] = *(const short8*)(&Bl[cur][0] + (wn * QN + t * 16 + lm) * 32 + q * 8);
#pragma unroll
    for (int i = 0; i < 4; ++i)
#pragma unroll
      for (int j = 0; j < NJ; ++j) acc[i][j] = MFMA16(af[i], bfr[j], acc[i][j]);
    __syncthreads();  // drains vmcnt(0) (next tile staged) + all waves done reading cur
    cur ^= 1;
  }

  if (EPI == 0) {
    // scatter to q_ws/k_ws [bh][l][64] (bf16 scalar) and vt_ws [bh][d][1024] (packed ushort4)
#pragma unroll
    for (int i = 0; i < 4; ++i) {
      int mb = m0 + wm * 64 + i * 16 + q * 4;  // multiple of 4 -> rg stays in one (b,l) row group
#pragma unroll
      for (int j = 0; j < NJ; ++j) {
        int n = n0 + wn * QN + j * 16 + lm;
        int which = n / 768;
        int r = n - which * 768;
        int h = r >> 6, d = r & 63;
        if (which == 2) {
          int b = mb >> 10, l = mb & 1023;  // mb..mb+3: same b, consecutive l
          ushort4 pk;
          pk.x = f2bf(acc[i][j][0]);
          pk.y = f2bf(acc[i][j][1]);
          pk.z = f2bf(acc[i][j][2]);
          pk.w = f2bf(acc[i][j][3]);
          *(ushort4*)(vt_ws + (size_t)((b * 12 + h) * 64 + d) * 1024 + l) = pk;
        } else {
          unsigned short* dst = (which == 0) ? q_ws : k_ws;
          float sc = (which == 0) ? 0.125f : 1.0f;  // fold attention scale into q (exact in bf16)
#pragma unroll
          for (int rg = 0; rg < 4; ++rg) {
            int m = mb + rg;
            int b = m >> 10, l = m & 1023;
            dst[(size_t)((b * 12 + h) * 1024 + l) * 64 + d] = f2bf(acc[i][j][rg] * sc);
          }
        }
      }
    }
  } else {
#pragma unroll
    for (int i = 0; i < 4; ++i) {
      int mb = m0 + wm * 64 + i * 16 + q * 4;
#pragma unroll
      for (int j = 0; j < NJ; ++j) {
        int n = n0 + wn * QN + j * 16 + lm;
        float bv = bias[n];
#pragma unroll
        for (int rg = 0; rg < 4; ++rg) {
          int m = mb + rg;
          Cout[(size_t)m * N + n] = acc[i][j][rg] + bv;
        }
      }
    }
  }
}

// ---------------- attention ----------------
// grid (64, 48): 16 query rows per block, 256 threads = 4 waves; wave owns 256 key cols.
// Swapped QK^T: C = MFMA(K_frag, Q_frag) -> C[m=key][n=q-row]; lane (q,lm) holds
// q-row lm, keys (wave*16+ct)*16 + q*4 + rg  => full row slice lives in acc[16][4] regs.
__global__ __launch_bounds__(256) void attn_mfma(
    const unsigned short* __restrict__ q_ws, const unsigned short* __restrict__ k_ws,
    const unsigned short* __restrict__ vt_ws, unsigned short* __restrict__ attn_o,
    float* __restrict__ out1) {
  constexpr int L = 1024, SW = 1032;  // stride: 16B-aligned rows (2064B = 516 banks, 4 mod 32)
  __shared__ __align__(16) unsigned short S[16 * SW];
  __shared__ float stats[2][4][16];  // [max|sum][wave][row]
  const int bh = blockIdx.y, b = bh / 12, h = bh % 12;
  const int l0 = blockIdx.x * 16;
  const int tid = threadIdx.x, lane = tid & 63, wave = tid >> 6;
  const int q = lane >> 4, lm = lane & 15;

  const size_t qk_base = (size_t)bh * L * 64;

  // Q as B-fragment: B[n=q-row=lm][k=q*8+j]; q pre-scaled by 0.125
  const unsigned short* qr = q_ws + qk_base + (size_t)(l0 + lm) * 64;
  short8 bq0 = *(const short8*)(qr + q * 8);
  short8 bq1 = *(const short8*)(qr + 32 + q * 8);

  // ---- swapped QK^T into registers ----
  floatx4 acc[16];
#pragma unroll
  for (int ct = 0; ct < 16; ++ct) {
    const unsigned short* kr = k_ws + qk_base + (size_t)((wave * 16 + ct) * 16 + lm) * 64;
    short8 a0 = *(const short8*)(kr + q * 8);
    short8 a1 = *(const short8*)(kr + 32 + q * 8);
    floatx4 c = (floatx4){0.f, 0.f, 0.f, 0.f};
    c = MFMA16(a0, bq0, c);
    c = MFMA16(a1, bq1, c);
    acc[ct] = c;
  }

  // ---- register softmax: row r = lm, spread over 4 lanes (q) x 16 cts ----
  float mloc = -1e30f;
#pragma unroll
  for (int ct = 0; ct < 16; ++ct)
#pragma unroll
    for (int rg = 0; rg < 4; ++rg) mloc = fmaxf(mloc, acc[ct][rg]);
  mloc = fmaxf(mloc, __shfl_xor(mloc, 16));
  mloc = fmaxf(mloc, __shfl_xor(mloc, 32));
  if (lane < 16) stats[0][wave][lane] = mloc;
  __syncthreads();
  float m = fmaxf(fmaxf(stats[0][0][lm], stats[0][1][lm]),
                  fmaxf(stats[0][2][lm], stats[0][3][lm]));

  float ssum = 0.f;
#pragma unroll
  for (int ct = 0; ct < 16; ++ct) {
#pragma unroll
    for (int rg = 0; rg < 4; ++rg) {
      float e = exp2f((acc[ct][rg] - m) * 1.44269504f);
      acc[ct][rg] = e;
      ssum += e;
    }
  }
  ssum += __shfl_xor(ssum, 16);
  ssum += __shfl_xor(ssum, 32);
  if (lane < 16) stats[1][wave][lane] = ssum;
  __syncthreads();
  float sinv = 1.0f / (stats[1][0][lm] + stats[1][1][lm] + stats[1][2][lm] + stats[1][3][lm]);

  // ---- write normalized S (bf16, for PV) + out1 (fp32) straight from registers ----
  float* orow = out1 + (size_t)bh * L * L + (size_t)(l0 + lm) * L + wave * 256 + q * 4;
  unsigned short* srow = S + lm * SW + wave * 256 + q * 4;
#pragma unroll
  for (int ct = 0; ct < 16; ++ct) {
    float p0 = acc[ct][0] * sinv, p1 = acc[ct][1] * sinv;
    float p2 = acc[ct][2] * sinv, p3 = acc[ct][3] * sinv;
    ushort4 pk;
    pk.x = f2bf(p0); pk.y = f2bf(p1); pk.z = f2bf(p2); pk.w = f2bf(p3);
    *(ushort4*)(srow + ct * 16) = pk;
    float4 pv;
    pv.x = p0; pv.y = p1; pv.z = p2; pv.w = p3;
    *(float4*)(orow + ct * 16) = pv;
  }
  __syncthreads();

  // ---- PV: wave owns d-tile [wave*16, wave*16+16); S pre-normalized ----
  {
    floatx4 pacc = (floatx4){0.f, 0.f, 0.f, 0.f};
    const unsigned short* vr = vt_ws + (size_t)(bh * 64 + wave * 16 + lm) * 1024;
#pragma unroll 4
    for (int ks = 0; ks < 32; ++ks) {
      short8 af = *(const short8*)(S + lm * SW + ks * 32 + q * 8);  // one ds_read_b128
      short8 bv = *(const short8*)(vr + ks * 32 + q * 8);
      pacc = MFMA16(af, bv, pacc);
    }
#pragma unroll
    for (int rg = 0; rg < 4; ++rg) {
      int row = q * 4 + rg;
      attn_o[(size_t)(b * 1024 + l0 + row) * 768 + h * 64 + wave * 16 + lm] = f2bf(pacc[rg]);
    }
  }
}

extern "C" void kernel_launch(void* const* d_in, const int* in_sizes, int n_in,
                              void* d_out, int out_size, void* d_ws, size_t ws_size,
                              hipStream_t stream) {
  const float* x      = (const float*)d_in[0];  // [4,1024,768]
  const float* w_qkv  = (const float*)d_in[1];  // [2304,768]
  const float* w_proj = (const float*)d_in[2];  // [768,768]
  const float* b_proj = (const float*)d_in[3];  // [768]

  float* out0 = (float*)d_out;                   // [4096,768]
  float* out1 = out0 + (size_t)4096 * 768;       // [48,1024,1024]

  const size_t NX = (size_t)4096 * 768;   // 3,145,728
  const size_t NWQ = (size_t)2304 * 768;  // 1,769,472
  const size_t NWP = (size_t)768 * 768;   //   589,824
  const size_t NQ = (size_t)48 * 1024 * 64;

  unsigned short* x_bf   = (unsigned short*)d_ws;
  unsigned short* wq_bf  = x_bf + NX;
  unsigned short* wp_bf  = wq_bf + NWQ;
  unsigned short* q_ws   = wp_bf + NWP;
  unsigned short* k_ws   = q_ws + NQ;
  unsigned short* vt_ws  = k_ws + NQ;
  unsigned short* attn_o = vt_ws + NQ;   // [4096][768] bf16

  // 1) fused casts (dst regions contiguous from x_bf)
  cast3_kernel<<<dim3((NX + NWQ + NWP) / 1024), dim3(256), 0, stream>>>(x, w_qkv, w_proj, x_bf);

  // 2) qkv GEMM + scatter  (128x128 tiles, 18x32 = 576 blocks)
  gemm_bt<0, 128><<<dim3(2304 / 128, 4096 / 128), dim3(256), 0, stream>>>(
      x_bf, wq_bf, nullptr, q_ws, k_ws, vt_ws, nullptr, 4096, 2304, 768);

  // 3) attention
  attn_mfma<<<dim3(64, 48), dim3(256), 0, stream>>>(q_ws, k_ws, vt_ws, attn_o, out1);

  // 4) proj GEMM + bias  (128x64 tiles, 12x32 = 384 blocks: full CU coverage)
  gemm_bt<1, 64><<<dim3(768 / 64, 4096 / 128), dim3(256), 0, stream>>>(
      attn_o, wp_bf, b_proj, nullptr, nullptr, nullptr, out0, 4096, 768, 768);
}

// Round 3
// 338.960 us; speedup vs baseline: 1.1202x; 1.0537x over previous
//
#include <hip/hip_runtime.h>
#include <hip/hip_bf16.h>
#include <stdint.h>

// B=4, L=1024, C=768, H=12, D=64.  All inputs/outputs fp32.
// Pipeline (all-MFMA bf16, fp32 accumulate):
//   c1: cast x, w_qkv, w_proj -> bf16 ws (single fused launch)
//   k1: qkv GEMM  [4096x768]@[2304x768]^T (128x128 tile, double-buffered prefetch)
//       -> scatter q(pre*0.125),k [bh][l][d], v^T [bh][d][l]  (bf16)
//   k2: attention per (bh, 16 rows): swapped QK^T -> online register softmax (1 publish,
//       2 barriers) -> out1 fp32 from regs + normalized bf16 S in LDS -> PV MFMA -> attn_o
//       XCD-swizzled 1D grid; setprio around MFMA clusters.
//   k3: proj GEMM  [4096x768]@[768x768]^T + bias (128x64 tile -> 384 blocks) -> out0 fp32

typedef __attribute__((ext_vector_type(8))) short short8;
typedef __attribute__((ext_vector_type(4))) float floatx4;

#define MFMA16(A_, B_, C_) __builtin_amdgcn_mfma_f32_16x16x32_bf16((A_), (B_), (C_), 0, 0, 0)

__device__ __forceinline__ unsigned short f2bf(float f) {
  unsigned u = __builtin_bit_cast(unsigned, f);
  u += 0x7FFFu + ((u >> 16) & 1u);   // round-to-nearest-even
  return (unsigned short)(u >> 16);
}
__device__ __forceinline__ float bf2f(unsigned short u) {
  return __builtin_bit_cast(float, (unsigned)u << 16);
}

// ---------------- fused cast fp32 -> bf16 (x, w_qkv, w_proj; contiguous dst) ----------------
__global__ __launch_bounds__(256) void cast3_kernel(const float* __restrict__ x,
                                                    const float* __restrict__ wq,
                                                    const float* __restrict__ wp,
                                                    unsigned short* __restrict__ dst) {
  const int NX = 3145728, NWQ = 1769472;  // region boundaries are block-aligned
  int i = (blockIdx.x * 256 + threadIdx.x) * 4;
  const float* src;
  int off;
  if (i < NX) { src = x; off = i; }
  else if (i < NX + NWQ) { src = wq; off = i - NX; }
  else { src = wp; off = i - NX - NWQ; }
  float4 v = *(const float4*)(src + off);
  ushort4 o;
  o.x = f2bf(v.x); o.y = f2bf(v.y); o.z = f2bf(v.z); o.w = f2bf(v.w);
  *(ushort4*)(dst + i) = o;
}

// ---------------- bf16 MFMA GEMM: C[M][N] = A[M][K] @ Bm[N][K]^T ----------------
// tile 128xBN, BK=32, 256 threads = 4 waves.  Wave (wm,wn) owns a 64x(BN/2) quadrant.
// Double-buffered LDS; next K-tile's global_load_lds issued BEFORE compute of current.
// EPI 0: qkv scatter epilogue (BN=128 only).  EPI 1: fp32 C + bias epilogue.
template <int EPI, int BN>
__global__ __launch_bounds__(256) void gemm_bt(
    const unsigned short* __restrict__ A, const unsigned short* __restrict__ Bm,
    const float* __restrict__ bias,
    unsigned short* __restrict__ q_ws, unsigned short* __restrict__ k_ws,
    unsigned short* __restrict__ vt_ws, float* __restrict__ Cout,
    int M, int N, int K) {
  constexpr int NJ = BN / 32;  // N-frags per wave (4 or 2)
  constexpr int QN = BN / 2;   // wave quadrant N-size (64 or 32)
  __shared__ __align__(16) unsigned short Al[2][128 * 32];
  __shared__ __align__(16) unsigned short Bl[2][BN * 32];
  const int tid = threadIdx.x;
  const int lane = tid & 63, wave = tid >> 6;
  const int q = lane >> 4, lm = lane & 15;
  const int wm = wave >> 1, wn = wave & 1;
  const int m0 = blockIdx.y * 128, n0 = blockIdx.x * BN;

  floatx4 acc[4][NJ];
#pragma unroll
  for (int i = 0; i < 4; ++i)
#pragma unroll
    for (int j = 0; j < NJ; ++j) acc[i][j] = (floatx4){0.f, 0.f, 0.f, 0.f};

  auto stage = [&](int k0, int buf) {
#pragma unroll
    for (int it = 0; it < 2; ++it) {
      int idx = tid + it * 256;
      int row = idx >> 2, ch = idx & 3;
      const unsigned short* ga = A + (size_t)(m0 + row) * K + k0 + ch * 8;
      __builtin_amdgcn_global_load_lds(
          (const __attribute__((address_space(1))) unsigned int*)ga,
          (__attribute__((address_space(3))) unsigned int*)(&Al[buf][0] + idx * 8), 16, 0, 0);
    }
#pragma unroll
    for (int it = 0; it < BN / 64; ++it) {
      int idx = tid + it * 256;
      int row = idx >> 2, ch = idx & 3;
      const unsigned short* gb = Bm + (size_t)(n0 + row) * K + k0 + ch * 8;
      __builtin_amdgcn_global_load_lds(
          (const __attribute__((address_space(1))) unsigned int*)gb,
          (__attribute__((address_space(3))) unsigned int*)(&Bl[buf][0] + idx * 8), 16, 0, 0);
    }
  };

  stage(0, 0);
  __syncthreads();
  int cur = 0;
  for (int k0 = 0; k0 < K; k0 += 32) {
    if (k0 + 32 < K) stage(k0 + 32, cur ^ 1);  // prefetch next tile, in flight during MFMA
    short8 af[4], bfr[NJ];
#pragma unroll
    for (int t = 0; t < 4; ++t)
      af[t] = *(const short8*)(&Al[cur][0] + (wm * 64 + t * 16 + lm) * 32 + q * 8);
#pragma unroll
    for (int t = 0; t < NJ; ++t)
      bfr[t] = *(const short8*)(&Bl[cur][0] + (wn * QN + t * 16 + lm) * 32 + q * 8);
#pragma unroll
    for (int i = 0; i < 4; ++i)
#pragma unroll
      for (int j = 0; j < NJ; ++j) acc[i][j] = MFMA16(af[i], bfr[j], acc[i][j]);
    __syncthreads();
    cur ^= 1;
  }

  if (EPI == 0) {
#pragma unroll
    for (int i = 0; i < 4; ++i) {
      int mb = m0 + wm * 64 + i * 16 + q * 4;  // multiple of 4 -> rg stays in one (b,l) row group
#pragma unroll
      for (int j = 0; j < NJ; ++j) {
        int n = n0 + wn * QN + j * 16 + lm;
        int which = n / 768;
        int r = n - which * 768;
        int h = r >> 6, d = r & 63;
        if (which == 2) {
          int b = mb >> 10, l = mb & 1023;  // mb..mb+3: same b, consecutive l
          ushort4 pk;
          pk.x = f2bf(acc[i][j][0]);
          pk.y = f2bf(acc[i][j][1]);
          pk.z = f2bf(acc[i][j][2]);
          pk.w = f2bf(acc[i][j][3]);
          *(ushort4*)(vt_ws + (size_t)((b * 12 + h) * 64 + d) * 1024 + l) = pk;
        } else {
          unsigned short* dst = (which == 0) ? q_ws : k_ws;
          float sc = (which == 0) ? 0.125f : 1.0f;  // fold attention scale into q
#pragma unroll
          for (int rg = 0; rg < 4; ++rg) {
            int m = mb + rg;
            int b = m >> 10, l = m & 1023;
            dst[(size_t)((b * 12 + h) * 1024 + l) * 64 + d] = f2bf(acc[i][j][rg] * sc);
          }
        }
      }
    }
  } else {
#pragma unroll
    for (int i = 0; i < 4; ++i) {
      int mb = m0 + wm * 64 + i * 16 + q * 4;
#pragma unroll
      for (int j = 0; j < NJ; ++j) {
        int n = n0 + wn * QN + j * 16 + lm;
        float bv = bias[n];
#pragma unroll
        for (int rg = 0; rg < 4; ++rg) {
          int m = mb + rg;
          Cout[(size_t)m * N + n] = acc[i][j][rg] + bv;
        }
      }
    }
  }
}

// ---------------- attention ----------------
// 1D grid 3072 (XCD-swizzled): 16 query rows per block, 256 threads = 4 waves.
// Swapped QK^T: C = MFMA(K_frag, Q_frag) -> lane (q,lm) holds q-row lm, keys
// (wave*16+ct)*16 + q*4 + rg => full row slice lives in acc[16][4] regs.
// Online softmax: exp vs wave-local max, single (mloc,ssum) publish, combine with
// e^(mloc-m) correction -> 2 barriers total.
__global__ __launch_bounds__(256) void attn_mfma(
    const unsigned short* __restrict__ q_ws, const unsigned short* __restrict__ k_ws,
    const unsigned short* __restrict__ vt_ws, unsigned short* __restrict__ attn_o,
    float* __restrict__ out1) {
  constexpr int L = 1024, SW = 1032;  // stride: 16B-aligned rows (2064B = 516 banks, 4 mod 32)
  constexpr float LOG2E = 1.44269504f;
  __shared__ __align__(16) unsigned short S[16 * SW];
  __shared__ float stats[2][4][16];  // [mloc|ssum][wave][row]
  // bijective XCD swizzle: 3072 blocks = 8 XCDs x 384; each XCD owns 6 consecutive bh
  // (1.5 MB K/V working set -> L2-resident instead of 8x L3 re-fetch).
  const int flat = blockIdx.x;
  const int swz = (flat & 7) * 384 + (flat >> 3);
  const int bh = swz >> 6, b = bh / 12, h = bh % 12;
  const int l0 = (swz & 63) * 16;
  const int tid = threadIdx.x, lane = tid & 63, wave = tid >> 6;
  const int q = lane >> 4, lm = lane & 15;

  const size_t qk_base = (size_t)bh * L * 64;

  // Q as B-fragment: B[n=q-row=lm][k=q*8+j]; q pre-scaled by 0.125
  const unsigned short* qr = q_ws + qk_base + (size_t)(l0 + lm) * 64;
  short8 bq0 = *(const short8*)(qr + q * 8);
  short8 bq1 = *(const short8*)(qr + 32 + q * 8);

  // ---- swapped QK^T into registers ----
  floatx4 acc[16];
  __builtin_amdgcn_s_setprio(1);
#pragma unroll
  for (int ct = 0; ct < 16; ++ct) {
    const unsigned short* kr = k_ws + qk_base + (size_t)((wave * 16 + ct) * 16 + lm) * 64;
    short8 a0 = *(const short8*)(kr + q * 8);
    short8 a1 = *(const short8*)(kr + 32 + q * 8);
    floatx4 c = (floatx4){0.f, 0.f, 0.f, 0.f};
    c = MFMA16(a0, bq0, c);
    c = MFMA16(a1, bq1, c);
    acc[ct] = c;
  }
  __builtin_amdgcn_s_setprio(0);

  // ---- online register softmax: row r = lm ----
  float mloc = -1e30f;
#pragma unroll
  for (int ct = 0; ct < 16; ++ct)
#pragma unroll
    for (int rg = 0; rg < 4; ++rg) mloc = fmaxf(mloc, acc[ct][rg]);
  mloc = fmaxf(mloc, __shfl_xor(mloc, 16));
  mloc = fmaxf(mloc, __shfl_xor(mloc, 32));

  float ssum = 0.f;
#pragma unroll
  for (int ct = 0; ct < 16; ++ct) {
#pragma unroll
    for (int rg = 0; rg < 4; ++rg) {
      float e = exp2f((acc[ct][rg] - mloc) * LOG2E);
      acc[ct][rg] = e;
      ssum += e;
    }
  }
  ssum += __shfl_xor(ssum, 16);
  ssum += __shfl_xor(ssum, 32);
  if (lane < 16) {
    stats[0][wave][lane] = mloc;
    stats[1][wave][lane] = ssum;
  }
  __syncthreads();  // B1: stats published

  float m0_ = stats[0][0][lm], m1_ = stats[0][1][lm];
  float m2_ = stats[0][2][lm], m3_ = stats[0][3][lm];
  float m = fmaxf(fmaxf(m0_, m1_), fmaxf(m2_, m3_));
  float sum = stats[1][0][lm] * exp2f((m0_ - m) * LOG2E)
            + stats[1][1][lm] * exp2f((m1_ - m) * LOG2E)
            + stats[1][2][lm] * exp2f((m2_ - m) * LOG2E)
            + stats[1][3][lm] * exp2f((m3_ - m) * LOG2E);
  float wscale = exp2f((mloc - m) * LOG2E) / sum;  // folds local-max correction + 1/sum

  // ---- write normalized S (bf16, for PV) + out1 (fp32) straight from registers ----
  float* orow = out1 + (size_t)bh * L * L + (size_t)(l0 + lm) * L + wave * 256 + q * 4;
  unsigned short* srow = S + lm * SW + wave * 256 + q * 4;
#pragma unroll
  for (int ct = 0; ct < 16; ++ct) {
    float p0 = acc[ct][0] * wscale, p1 = acc[ct][1] * wscale;
    float p2 = acc[ct][2] * wscale, p3 = acc[ct][3] * wscale;
    ushort4 pk;
    pk.x = f2bf(p0); pk.y = f2bf(p1); pk.z = f2bf(p2); pk.w = f2bf(p3);
    *(ushort4*)(srow + ct * 16) = pk;
    float4 pv;
    pv.x = p0; pv.y = p1; pv.z = p2; pv.w = p3;
    *(float4*)(orow + ct * 16) = pv;
  }
  __syncthreads();  // B2: S ready

  // ---- PV: wave owns d-tile [wave*16, wave*16+16); S pre-normalized ----
  {
    floatx4 pacc = (floatx4){0.f, 0.f, 0.f, 0.f};
    const unsigned short* vr = vt_ws + (size_t)(bh * 64 + wave * 16 + lm) * 1024;
    __builtin_amdgcn_s_setprio(1);
#pragma unroll 4
    for (int ks = 0; ks < 32; ++ks) {
      short8 af = *(const short8*)(S + lm * SW + ks * 32 + q * 8);  // one ds_read_b128
      short8 bv = *(const short8*)(vr + ks * 32 + q * 8);
      pacc = MFMA16(af, bv, pacc);
    }
    __builtin_amdgcn_s_setprio(0);
#pragma unroll
    for (int rg = 0; rg < 4; ++rg) {
      int row = q * 4 + rg;
      attn_o[(size_t)(b * 1024 + l0 + row) * 768 + h * 64 + wave * 16 + lm] = f2bf(pacc[rg]);
    }
  }
}

extern "C" void kernel_launch(void* const* d_in, const int* in_sizes, int n_in,
                              void* d_out, int out_size, void* d_ws, size_t ws_size,
                              hipStream_t stream) {
  const float* x      = (const float*)d_in[0];  // [4,1024,768]
  const float* w_qkv  = (const float*)d_in[1];  // [2304,768]
  const float* w_proj = (const float*)d_in[2];  // [768,768]
  const float* b_proj = (const float*)d_in[3];  // [768]

  float* out0 = (float*)d_out;                   // [4096,768]
  float* out1 = out0 + (size_t)4096 * 768;       // [48,1024,1024]

  const size_t NX = (size_t)4096 * 768;   // 3,145,728
  const size_t NWQ = (size_t)2304 * 768;  // 1,769,472
  const size_t NWP = (size_t)768 * 768;   //   589,824
  const size_t NQ = (size_t)48 * 1024 * 64;

  unsigned short* x_bf   = (unsigned short*)d_ws;
  unsigned short* wq_bf  = x_bf + NX;
  unsigned short* wp_bf  = wq_bf + NWQ;
  unsigned short* q_ws   = wp_bf + NWP;
  unsigned short* k_ws   = q_ws + NQ;
  unsigned short* vt_ws  = k_ws + NQ;
  unsigned short* attn_o = vt_ws + NQ;   // [4096][768] bf16

  // 1) fused casts (dst regions contiguous from x_bf)
  cast3_kernel<<<dim3((NX + NWQ + NWP) / 1024), dim3(256), 0, stream>>>(x, w_qkv, w_proj, x_bf);

  // 2) qkv GEMM + scatter  (128x128 tiles, 18x32 = 576 blocks)
  gemm_bt<0, 128><<<dim3(2304 / 128, 4096 / 128), dim3(256), 0, stream>>>(
      x_bf, wq_bf, nullptr, q_ws, k_ws, vt_ws, nullptr, 4096, 2304, 768);

  // 3) attention (1D XCD-swizzled grid)
  attn_mfma<<<dim3(3072), dim3(256), 0, stream>>>(q_ws, k_ws, vt_ws, attn_o, out1);

  // 4) proj GEMM + bias  (128x64 tiles, 12x32 = 384 blocks: full CU coverage)
  gemm_bt<1, 64><<<dim3(768 / 64, 4096 / 128), dim3(256), 0, stream>>>(
      attn_o, wp_bf, b_proj, nullptr, nullptr, nullptr, out0, 4096, 768, 768);
}